// Round 11
// baseline (2346.227 us; speedup 1.0000x reference)
//
#include <hip/hip_runtime.h>
#include <math.h>

#define NN 10000
#define NE 320000
#define DD 256
#define KSEL 8000
#define KK 512
#define NPART 157
#define REPS 16            // probe repetition factor

typedef unsigned int uint;
typedef unsigned short ushort;
typedef __attribute__((ext_vector_type(8))) short short8;
typedef __attribute__((ext_vector_type(4))) float f32x4;
typedef __attribute__((ext_vector_type(4))) ushort us4;
typedef __attribute__((ext_vector_type(8))) ushort us8;

__device__ __forceinline__ void atomAddF(float* p, float v) {
    unsafeAtomicAdd(p, v);
}

__device__ __forceinline__ uint encodeF(float f) {
    uint u = __float_as_uint(f);
    return (u & 0x80000000u) ? ~u : (u | 0x80000000u);
}

__device__ __forceinline__ ushort f2bf(float f) {
    uint u = __float_as_uint(f);
    u += 0x7FFFu + ((u >> 16) & 1u);
    return (ushort)(u >> 16);
}

// ---------------- 0. zero degi/y/cbuf/rbuf/cnt/cursorp/cntp ---------------
// 4*40000 + 64 + 40000 + 64 = 200128 B = 12508 quads, contiguous
#define ZQUADS 12508
__global__ __launch_bounds__(256) void zero_bufs(float4* __restrict__ z) {
    int i = blockIdx.x * 256 + threadIdx.x;
    if (i < ZQUADS) z[i] = make_float4(0.f, 0.f, 0.f, 0.f);
}

// ---------------- 1. prep: W-transpose + cast_h + count_deg ---------------
#define WB 32
#define HB 2500
#define DB 1250
__global__ __launch_bounds__(256) void prep(
    const float* __restrict__ h, const float* __restrict__ W_l,
    const float* __restrict__ W_r, const int* __restrict__ ei,
    ushort* __restrict__ Ab, ushort* __restrict__ Wt,
    int* __restrict__ degi) {
    const int b = blockIdx.x, t = threadIdx.x;
    if (b < WB) {
        __shared__ float tile[64][65];
        const int tr = b >> 2, tc = b & 3;
        const int k0 = tr * 64, n0 = tc * 64;
        const int r = t >> 6, c = t & 63;
        const float* Wsrc = (k0 < 256) ? (W_l + (size_t)k0 * DD)
                                       : (W_r + (size_t)(k0 - 256) * DD);
#pragma unroll
        for (int i = 0; i < 16; i++) {
            int row = r + i * 4;
            tile[row][c] = Wsrc[(size_t)row * DD + n0 + c];
        }
        __syncthreads();
#pragma unroll
        for (int i = 0; i < 16; i++) {
            int row = r + i * 4;
            Wt[(size_t)(n0 + row) * KK + k0 + c] = f2bf(tile[c][row]);
        }
    } else if (b < WB + HB) {
        int id = (b - WB) * 256 + t;
        int node = id >> 6, seg = (id & 63) * 4;
        float4 v = *(const float4*)(h + (size_t)node * DD + seg);
        us4 o;
        o[0] = f2bf(v.x); o[1] = f2bf(v.y); o[2] = f2bf(v.z); o[3] = f2bf(v.w);
        *(us4*)(Ab + (size_t)node * KK + 256 + seg) = o;
    } else {
        int e = (b - WB - HB) * 256 + t;
        if (e < NE) atomicAdd(&degi[ei[NE + e]], 1);
    }
}

// ---------------- 2. single-block prefix scan -----------------------------
__global__ __launch_bounds__(1024) void scan_start(
    const int* __restrict__ degi, int* __restrict__ start,
    int* __restrict__ cursor, float* __restrict__ invdeg) {
    __shared__ int partial[1024];
    const int t  = threadIdx.x;
    const int CH = (NN + 1023) / 1024;
    const int base = t * CH;
    int sum = 0;
#pragma unroll
    for (int i = 0; i < CH; i++) {
        int idx = base + i;
        if (idx < NN) sum += degi[idx];
    }
    partial[t] = sum;
    __syncthreads();
    for (int off = 1; off < 1024; off <<= 1) {
        int add = (t >= off) ? partial[t - off] : 0;
        __syncthreads();
        partial[t] += add;
        __syncthreads();
    }
    int run = partial[t] - sum;
#pragma unroll
    for (int i = 0; i < CH; i++) {
        int idx = base + i;
        if (idx < NN) {
            start[idx]  = run;
            cursor[idx] = run;
            int d = degi[idx];
            invdeg[idx] = 1.0f / fmaxf((float)d, 1.0f);
            run += d;
        }
    }
    if (t == 1023) start[NN] = NE;
}

// ---------------- 3. fill CSR ---------------------------------------------
__global__ __launch_bounds__(256) void fill_csr(
    const int* __restrict__ ei, int* __restrict__ cursor,
    int* __restrict__ csr) {
    int e = blockIdx.x * 256 + threadIdx.x;
    if (e >= NE) return;
    int pos = atomicAdd(&cursor[ei[NE + e]], 1);
    csr[pos] = ei[e];
}

// ---------------- 4. gather mean ------------------------------------------
__global__ __launch_bounds__(256) void gather_mean(
    ushort* __restrict__ Ab, const int* __restrict__ csr,
    const int* __restrict__ start, const float* __restrict__ invdeg) {
    int node = blockIdx.x * 4 + (threadIdx.x >> 6);
    int lane = threadIdx.x & 63;
    if (node >= NN) return;
    int s = start[node], e = start[node + 1];
    const ushort* hb = Ab + 256 + lane * 4;
    float4 A0 = make_float4(0.f, 0.f, 0.f, 0.f);
    float4 A1 = make_float4(0.f, 0.f, 0.f, 0.f);
    int j = s;
    for (; j + 2 <= e; j += 2) {
        int s0 = csr[j], s1 = csr[j + 1];
        uint2 v0 = *(const uint2*)(hb + (size_t)s0 * KK);
        uint2 v1 = *(const uint2*)(hb + (size_t)s1 * KK);
        A0.x += __uint_as_float(v0.x << 16);
        A0.y += __uint_as_float(v0.x & 0xFFFF0000u);
        A0.z += __uint_as_float(v0.y << 16);
        A0.w += __uint_as_float(v0.y & 0xFFFF0000u);
        A1.x += __uint_as_float(v1.x << 16);
        A1.y += __uint_as_float(v1.x & 0xFFFF0000u);
        A1.z += __uint_as_float(v1.y << 16);
        A1.w += __uint_as_float(v1.y & 0xFFFF0000u);
    }
    for (; j < e; j++) {
        uint2 v0 = *(const uint2*)(hb + (size_t)csr[j] * KK);
        A0.x += __uint_as_float(v0.x << 16);
        A0.y += __uint_as_float(v0.x & 0xFFFF0000u);
        A0.z += __uint_as_float(v0.y << 16);
        A0.w += __uint_as_float(v0.y & 0xFFFF0000u);
    }
    float id = invdeg[node];
    us4 m;
    m[0] = f2bf((A0.x + A1.x) * id);
    m[1] = f2bf((A0.y + A1.y) * id);
    m[2] = f2bf((A0.z + A1.z) * id);
    m[3] = f2bf((A0.w + A1.w) * id);
    *(us4*)(Ab + (size_t)node * KK + lane * 4) = m;
}

// ---------------- 5. MFMA GEMM --------------------------------------------
__global__ __launch_bounds__(256) void gemm_x(
    const ushort* __restrict__ Ab, const ushort* __restrict__ Wt,
    const float* __restrict__ b_l,
    const float* __restrict__ W_rel, const float* __restrict__ W_gate,
    const float* __restrict__ W_root,
    float* __restrict__ xout, float* __restrict__ y,
    float* __restrict__ cvec, float* __restrict__ rvec) {
    __shared__ ushort Asm[2][32][40];
    __shared__ ushort Bsm[2][256][40];
    const int t    = threadIdx.x;
    const int row0 = blockIdx.x * 32;
    const int wid  = t >> 6, lane = t & 63;
    const int l15  = lane & 15, g = lane >> 4;

    f32x4 acc[2][4];
#pragma unroll
    for (int fi = 0; fi < 2; fi++)
#pragma unroll
        for (int fj = 0; fj < 4; fj++) acc[fi][fj] = (f32x4)0.f;

    const int  arow = t >> 3, akseg = (t & 7) * 4;
    const bool aok  = (row0 + arow) < NN;
    const ushort* aptr = Ab + (size_t)(row0 + arow) * KK + akseg;
    const ushort* bptr = Wt + (size_t)t * KK;

    us4 areg = {0, 0, 0, 0};
    us8 breg[4];
    if (aok) areg = *(const us4*)(aptr);
#pragma unroll
    for (int jj = 0; jj < 4; jj++) breg[jj] = *(const us8*)(bptr + jj * 8);
    *(us4*)&Asm[0][arow][akseg] = areg;
#pragma unroll
    for (int jj = 0; jj < 4; jj++) *(us8*)&Bsm[0][t][jj * 8] = breg[jj];
    __syncthreads();

    for (int ks = 0; ks < 16; ++ks) {
        const int cur = ks & 1;
        if (ks < 15) {
            const int k0 = (ks + 1) * 32;
            if (aok) areg = *(const us4*)(aptr + k0);
#pragma unroll
            for (int jj = 0; jj < 4; jj++) breg[jj] = *(const us8*)(bptr + k0 + jj * 8);
        }
        short8 af0 = *(const short8*)&Asm[cur][l15][g * 8];
        short8 af1 = *(const short8*)&Asm[cur][16 + l15][g * 8];
#pragma unroll
        for (int fj = 0; fj < 4; fj++) {
            short8 bf = *(const short8*)&Bsm[cur][wid * 64 + fj * 16 + l15][g * 8];
            acc[0][fj] = __builtin_amdgcn_mfma_f32_16x16x32_bf16(af0, bf, acc[0][fj], 0, 0, 0);
            acc[1][fj] = __builtin_amdgcn_mfma_f32_16x16x32_bf16(af1, bf, acc[1][fj], 0, 0, 0);
        }
        if (ks < 15) {
            const int nb = cur ^ 1;
            *(us4*)&Asm[nb][arow][akseg] = areg;
#pragma unroll
            for (int jj = 0; jj < 4; jj++) *(us8*)&Bsm[nb][t][jj * 8] = breg[jj];
        }
        __syncthreads();
    }

    const int wcol0 = wid * 64;
    float bl[4], wl[4], wg[4], wo[4];
#pragma unroll
    for (int fj = 0; fj < 4; fj++) {
        int col = wcol0 + fj * 16 + l15;
        bl[fj] = b_l[col]; wl[fj] = W_rel[col];
        wg[fj] = W_gate[col]; wo[fj] = W_root[col];
    }
#pragma unroll
    for (int fi = 0; fi < 2; fi++) {
#pragma unroll
        for (int r = 0; r < 4; r++) {
            int row = row0 + fi * 16 + g * 4 + r;
            if (row >= NN) continue;
            float py = 0.f, pc = 0.f, pr = 0.f;
#pragma unroll
            for (int fj = 0; fj < 4; fj++) {
                float v = fmaxf(acc[fi][fj][r] + bl[fj], 0.f);
                xout[(size_t)row * DD + wcol0 + fj * 16 + l15] = v;
                py = fmaf(v, wl[fj], py);
                pc = fmaf(v, wg[fj], pc);
                pr = fmaf(v, wo[fj], pr);
            }
#pragma unroll
            for (int off = 1; off < 16; off <<= 1) {
                py += __shfl_xor(py, off);
                pc += __shfl_xor(pc, off);
                pr += __shfl_xor(pr, off);
            }
            if (l15 == 0) {
                atomAddF(y + row, py);
                atomAddF(cvec + row, pc);
                atomAddF(rvec + row, pr);
            }
        }
    }
}

// ---------------- 6. gather y + score + key -------------------------------
__global__ __launch_bounds__(256) void gather_score(
    const float* __restrict__ y, const float* __restrict__ r,
    const float* __restrict__ b_rel, const int* __restrict__ csr,
    const int* __restrict__ start,
    float* __restrict__ score, uint* __restrict__ key) {
    int gt   = blockIdx.x * 256 + threadIdx.x;
    int node = gt >> 4, l = gt & 15;
    if (node >= NN) return;
    int s = start[node], e = start[node + 1];
    float acc = 0.f;
    for (int j = s + l; j < e; j += 16) acc += y[csr[j]];
#pragma unroll
    for (int o = 8; o; o >>= 1) acc += __shfl_xor(acc, o, 16);
    if (l == 0) {
        float sc = tanhf(acc + b_rel[0] + r[node]);
        score[node] = sc;
        key[node]   = encodeF(sc);
    }
}

// ---------------- 7. radix select + max + weights + denom -----------------
__global__ __launch_bounds__(1024) void radix_select(
    const uint* __restrict__ key, const float* __restrict__ score,
    const float* __restrict__ cvec,
    float* __restrict__ wsc, float* __restrict__ denom) {
    __shared__ uint  hist[256];
    __shared__ uint  ssum[256];
    __shared__ uint  sh_prefix, sh_need;
    __shared__ float wred[16];
    __shared__ uint  tick_s;
    const int t = threadIdx.x;
    uint prefix = 0, pmask = 0, need = KSEL;
    float vmax = -INFINITY;
    for (int shift = 24; shift >= 0; shift -= 8) {
        if (t < 256) hist[t] = 0;
        __syncthreads();
        if (shift == 0) {
            for (int i = t; i < NN; i += 1024) {
                uint k = key[i];
                if ((k & pmask) == prefix) atomicAdd(&hist[k & 255], 1u);
                if (k >= prefix) vmax = fmaxf(vmax, score[i] * cvec[i]);
            }
        } else {
            for (int i = t; i < NN; i += 1024) {
                uint k = key[i];
                if ((k & pmask) == prefix) atomicAdd(&hist[(k >> shift) & 255], 1u);
            }
        }
        __syncthreads();
        if (t < 256) ssum[t] = hist[t];
        __syncthreads();
        for (int off = 1; off < 256; off <<= 1) {
            uint add = 0;
            if (t < 256 && t + off < 256) add = ssum[t + off];
            __syncthreads();
            if (t < 256) ssum[t] += add;
            __syncthreads();
        }
        if (t < 256) {
            uint hi = ssum[t];
            uint lo = (t < 255) ? ssum[t + 1] : 0u;
            if (need <= hi && need > lo) {
                sh_prefix = prefix | ((uint)t << shift);
                sh_need   = need - lo;
            }
        }
        __syncthreads();
        prefix = sh_prefix;
        need   = sh_need;
        pmask |= (0xFFu << shift);
        __syncthreads();
    }
    const uint T      = prefix;
    const uint needEq = need;
#pragma unroll
    for (int o = 32; o; o >>= 1) vmax = fmaxf(vmax, __shfl_xor(vmax, o));
    if ((t & 63) == 0) wred[t >> 6] = vmax;
    if (t == 0) tick_s = 0;
    __syncthreads();
    float m = wred[0];
#pragma unroll
    for (int w = 1; w < 16; w++) m = fmaxf(m, wred[w]);
    __syncthreads();
    float dsum = 0.f;
    for (int i = t; i < NN; i += 1024) {
        uint k = key[i];
        bool selm = (k > T);
        if (k == T) selm = (atomicAdd(&tick_s, 1u) < needEq);
        float wv = 0.f;
        if (selm) {
            float s = score[i];
            float w = expf(s * cvec[i] - m);
            wv   = w * s;
            dsum += w;
        }
        wsc[i] = wv;
    }
#pragma unroll
    for (int o = 32; o; o >>= 1) dsum += __shfl_xor(dsum, o);
    if ((t & 63) == 0) wred[t >> 6] = dsum;
    __syncthreads();
    if (t == 0) {
        float d = 0.f;
#pragma unroll
        for (int w = 0; w < 16; w++) d += wred[w];
        denom[0] = d;
    }
}

// ---------------- 8. weighted row-sum + last-block finalize ---------------
__global__ __launch_bounds__(256) void reduce_rows(
    const float* __restrict__ x, const float* __restrict__ wsc,
    float* __restrict__ part, uint* __restrict__ counter,
    const float* __restrict__ denom, float* __restrict__ out) {
    __shared__ float red[3][DD];
    __shared__ uint  lastdone;
    const int wave = threadIdx.x >> 6;
    const int lane = threadIdx.x & 63;
    const int row0 = (blockIdx.x * 4 + wave) * 16;
    const float* xp = x + lane * 4;
    float4 acc = make_float4(0.f, 0.f, 0.f, 0.f);
    if (row0 < NN) {
#pragma unroll
        for (int rb = 0; rb < 16; rb += 4) {
            int r0 = row0 + rb;
            float w0 = wsc[r0 + 0], w1 = wsc[r0 + 1];
            float w2 = wsc[r0 + 2], w3 = wsc[r0 + 3];
            float4 v0 = *(const float4*)(xp + (size_t)(r0 + 0) * DD);
            float4 v1 = *(const float4*)(xp + (size_t)(r0 + 1) * DD);
            float4 v2 = *(const float4*)(xp + (size_t)(r0 + 2) * DD);
            float4 v3 = *(const float4*)(xp + (size_t)(r0 + 3) * DD);
            acc.x = fmaf(w0, v0.x, fmaf(w1, v1.x, fmaf(w2, v2.x, fmaf(w3, v3.x, acc.x))));
            acc.y = fmaf(w0, v0.y, fmaf(w1, v1.y, fmaf(w2, v2.y, fmaf(w3, v3.y, acc.y))));
            acc.z = fmaf(w0, v0.z, fmaf(w1, v1.z, fmaf(w2, v2.z, fmaf(w3, v3.z, acc.z))));
            acc.w = fmaf(w0, v0.w, fmaf(w1, v1.w, fmaf(w2, v2.w, fmaf(w3, v3.w, acc.w))));
        }
    }
    if (wave > 0) *(float4*)&red[wave - 1][lane * 4] = acc;
    __syncthreads();
    if (wave == 0) {
#pragma unroll
        for (int w = 0; w < 3; w++) {
            float4 rv = *(float4*)&red[w][lane * 4];
            acc.x += rv.x; acc.y += rv.y; acc.z += rv.z; acc.w += rv.w;
        }
        *(float4*)(part + (size_t)blockIdx.x * DD + lane * 4) = acc;
    }
    __threadfence();
    if (threadIdx.x == 0) lastdone = atomicAdd(counter, 1u);
    __syncthreads();
    if (lastdone == NPART - 1) {
        __threadfence();
        int i = threadIdx.x;
        float s = 0.f;
        for (int b = 0; b < NPART; b++) s += part[(size_t)b * DD + i];
        out[i] = s / denom[0];
    }
}

// ======================= PROBES (x16, scratch outputs) ====================
#define PROBE_LOOP for (int rep = 0; rep < REPS; ++rep)
#define PROBE_FENCE asm volatile("" ::: "memory")

__global__ __launch_bounds__(256) void prep_p(
    const float* __restrict__ h, const float* __restrict__ W_l,
    const float* __restrict__ W_r, const int* __restrict__ ei,
    ushort* __restrict__ Abp, ushort* __restrict__ Wtp,
    int* __restrict__ degi) {
    __shared__ float tile[64][65];
    const int b = blockIdx.x, t = threadIdx.x;
    PROBE_LOOP {
        PROBE_FENCE;
        __syncthreads();
        if (b < WB) {
            const int tr = b >> 2, tc = b & 3;
            const int k0 = tr * 64, n0 = tc * 64;
            const int r = t >> 6, c = t & 63;
            const float* Wsrc = (k0 < 256) ? (W_l + (size_t)k0 * DD)
                                           : (W_r + (size_t)(k0 - 256) * DD);
#pragma unroll
            for (int i = 0; i < 16; i++) {
                int row = r + i * 4;
                tile[row][c] = Wsrc[(size_t)row * DD + n0 + c];
            }
            __syncthreads();
#pragma unroll
            for (int i = 0; i < 16; i++) {
                int row = r + i * 4;
                Wtp[(size_t)(n0 + row) * KK + k0 + c] = f2bf(tile[c][row]);
            }
        } else if (b < WB + HB) {
            int id = (b - WB) * 256 + t;
            int node = id >> 6, seg = (id & 63) * 4;
            float4 v = *(const float4*)(h + (size_t)node * DD + seg);
            us4 o;
            o[0] = f2bf(v.x); o[1] = f2bf(v.y); o[2] = f2bf(v.z); o[3] = f2bf(v.w);
            *(us4*)(Abp + (size_t)node * KK + 256 + seg) = o;
        } else {
            int e = (b - WB - HB) * 256 + t;
            if (e < NE) atomicAdd(&degi[ei[NE + e]], 1);   // degi dead post-scan
        }
    }
}

__global__ __launch_bounds__(1024) void scan_p(
    const int* __restrict__ degi, int* __restrict__ startp,
    int* __restrict__ cursorq, float* __restrict__ invdegp) {
    __shared__ int partial[1024];
    const int t  = threadIdx.x;
    PROBE_LOOP {
        PROBE_FENCE;
        __syncthreads();
        const int CH = (NN + 1023) / 1024;
        const int base = t * CH;
        int sum = 0;
#pragma unroll
        for (int i = 0; i < CH; i++) {
            int idx = base + i;
            if (idx < NN) sum += degi[idx];
        }
        partial[t] = sum;
        __syncthreads();
        for (int off = 1; off < 1024; off <<= 1) {
            int add = (t >= off) ? partial[t - off] : 0;
            __syncthreads();
            partial[t] += add;
            __syncthreads();
        }
        int run = partial[t] - sum;
#pragma unroll
        for (int i = 0; i < CH; i++) {
            int idx = base + i;
            if (idx < NN) {
                startp[idx]  = run;
                cursorq[idx] = run;
                int d = degi[idx];
                invdegp[idx] = 1.0f / fmaxf((float)d, 1.0f);
                run += d;
            }
        }
        if (t == 1023) startp[NN] = NE;
    }
}

__global__ __launch_bounds__(256) void fillcsr_p(
    const int* __restrict__ ei, int* __restrict__ cursorp,
    const int* __restrict__ start, int* __restrict__ csr2) {
    int e = blockIdx.x * 256 + threadIdx.x;
    PROBE_LOOP {
        PROBE_FENCE;
        if (e < NE) {
            int d = ei[NE + e];
            int pos = atomicAdd(&cursorp[d], 1);
            uint idx = (uint)(start[d] + pos) % (uint)NE;
            csr2[idx] = ei[e];
        }
    }
}

__global__ __launch_bounds__(256) void gmean_p(
    const ushort* __restrict__ Ab, ushort* __restrict__ Abp,
    const int* __restrict__ csr,
    const int* __restrict__ start, const float* __restrict__ invdeg) {
    int node = blockIdx.x * 4 + (threadIdx.x >> 6);
    int lane = threadIdx.x & 63;
    PROBE_LOOP {
        PROBE_FENCE;
        if (node < NN) {
            int s = start[node], e = start[node + 1];
            const ushort* hb = Ab + 256 + lane * 4;
            float4 A0 = make_float4(0.f, 0.f, 0.f, 0.f);
            float4 A1 = make_float4(0.f, 0.f, 0.f, 0.f);
            int j = s;
            for (; j + 2 <= e; j += 2) {
                int s0 = csr[j], s1 = csr[j + 1];
                uint2 v0 = *(const uint2*)(hb + (size_t)s0 * KK);
                uint2 v1 = *(const uint2*)(hb + (size_t)s1 * KK);
                A0.x += __uint_as_float(v0.x << 16);
                A0.y += __uint_as_float(v0.x & 0xFFFF0000u);
                A0.z += __uint_as_float(v0.y << 16);
                A0.w += __uint_as_float(v0.y & 0xFFFF0000u);
                A1.x += __uint_as_float(v1.x << 16);
                A1.y += __uint_as_float(v1.x & 0xFFFF0000u);
                A1.z += __uint_as_float(v1.y << 16);
                A1.w += __uint_as_float(v1.y & 0xFFFF0000u);
            }
            for (; j < e; j++) {
                uint2 v0 = *(const uint2*)(hb + (size_t)csr[j] * KK);
                A0.x += __uint_as_float(v0.x << 16);
                A0.y += __uint_as_float(v0.x & 0xFFFF0000u);
                A0.z += __uint_as_float(v0.y << 16);
                A0.w += __uint_as_float(v0.y & 0xFFFF0000u);
            }
            float id = invdeg[node];
            us4 m;
            m[0] = f2bf((A0.x + A1.x) * id);
            m[1] = f2bf((A0.y + A1.y) * id);
            m[2] = f2bf((A0.z + A1.z) * id);
            m[3] = f2bf((A0.w + A1.w) * id);
            *(us4*)(Abp + (size_t)node * KK + lane * 4) = m;
        }
    }
}

__global__ __launch_bounds__(256) void gemm_p(
    const ushort* __restrict__ Ab, const ushort* __restrict__ Wt,
    const float* __restrict__ b_l,
    const float* __restrict__ W_rel, const float* __restrict__ W_gate,
    const float* __restrict__ W_root,
    float* __restrict__ xoutp, float* __restrict__ yp,
    float* __restrict__ cp, float* __restrict__ rp) {
    __shared__ ushort Asm[2][32][40];
    __shared__ ushort Bsm[2][256][40];
    const int t    = threadIdx.x;
    const int row0 = blockIdx.x * 32;
    const int wid  = t >> 6, lane = t & 63;
    const int l15  = lane & 15, g = lane >> 4;
    PROBE_LOOP {
        PROBE_FENCE;
        __syncthreads();
        f32x4 acc[2][4];
#pragma unroll
        for (int fi = 0; fi < 2; fi++)
#pragma unroll
            for (int fj = 0; fj < 4; fj++) acc[fi][fj] = (f32x4)0.f;
        const int  arow = t >> 3, akseg = (t & 7) * 4;
        const bool aok  = (row0 + arow) < NN;
        const ushort* aptr = Ab + (size_t)(row0 + arow) * KK + akseg;
        const ushort* bptr = Wt + (size_t)t * KK;
        us4 areg = {0, 0, 0, 0};
        us8 breg[4];
        if (aok) areg = *(const us4*)(aptr);
#pragma unroll
        for (int jj = 0; jj < 4; jj++) breg[jj] = *(const us8*)(bptr + jj * 8);
        *(us4*)&Asm[0][arow][akseg] = areg;
#pragma unroll
        for (int jj = 0; jj < 4; jj++) *(us8*)&Bsm[0][t][jj * 8] = breg[jj];
        __syncthreads();
        for (int ks = 0; ks < 16; ++ks) {
            const int cur = ks & 1;
            if (ks < 15) {
                const int k0 = (ks + 1) * 32;
                if (aok) areg = *(const us4*)(aptr + k0);
#pragma unroll
                for (int jj = 0; jj < 4; jj++) breg[jj] = *(const us8*)(bptr + k0 + jj * 8);
            }
            short8 af0 = *(const short8*)&Asm[cur][l15][g * 8];
            short8 af1 = *(const short8*)&Asm[cur][16 + l15][g * 8];
#pragma unroll
            for (int fj = 0; fj < 4; fj++) {
                short8 bf = *(const short8*)&Bsm[cur][wid * 64 + fj * 16 + l15][g * 8];
                acc[0][fj] = __builtin_amdgcn_mfma_f32_16x16x32_bf16(af0, bf, acc[0][fj], 0, 0, 0);
                acc[1][fj] = __builtin_amdgcn_mfma_f32_16x16x32_bf16(af1, bf, acc[1][fj], 0, 0, 0);
            }
            if (ks < 15) {
                const int nb = cur ^ 1;
                *(us4*)&Asm[nb][arow][akseg] = areg;
#pragma unroll
                for (int jj = 0; jj < 4; jj++) *(us8*)&Bsm[nb][t][jj * 8] = breg[jj];
            }
            __syncthreads();
        }
        const int wcol0 = wid * 64;
        float bl[4], wl[4], wg[4], wo[4];
#pragma unroll
        for (int fj = 0; fj < 4; fj++) {
            int col = wcol0 + fj * 16 + l15;
            bl[fj] = b_l[col]; wl[fj] = W_rel[col];
            wg[fj] = W_gate[col]; wo[fj] = W_root[col];
        }
#pragma unroll
        for (int fi = 0; fi < 2; fi++) {
#pragma unroll
            for (int r = 0; r < 4; r++) {
                int row = row0 + fi * 16 + g * 4 + r;
                if (row >= NN) continue;
                float py = 0.f, pc = 0.f, pr = 0.f;
#pragma unroll
                for (int fj = 0; fj < 4; fj++) {
                    float v = fmaxf(acc[fi][fj][r] + bl[fj], 0.f);
                    xoutp[(size_t)row * DD + wcol0 + fj * 16 + l15] = v;
                    py = fmaf(v, wl[fj], py);
                    pc = fmaf(v, wg[fj], pc);
                    pr = fmaf(v, wo[fj], pr);
                }
#pragma unroll
                for (int off = 1; off < 16; off <<= 1) {
                    py += __shfl_xor(py, off);
                    pc += __shfl_xor(pc, off);
                    pr += __shfl_xor(pr, off);
                }
                if (l15 == 0) {
                    atomAddF(yp + row, py);
                    atomAddF(cp + row, pc);
                    atomAddF(rp + row, pr);
                }
            }
        }
    }
}

__global__ __launch_bounds__(256) void gscore_p(
    const float* __restrict__ y, const float* __restrict__ r,
    const float* __restrict__ b_rel, const int* __restrict__ csr,
    const int* __restrict__ start,
    float* __restrict__ scorep, uint* __restrict__ keyp) {
    int gt   = blockIdx.x * 256 + threadIdx.x;
    int node = gt >> 4, l = gt & 15;
    PROBE_LOOP {
        PROBE_FENCE;
        if (node < NN) {
            int s = start[node], e = start[node + 1];
            float acc = 0.f;
            for (int j = s + l; j < e; j += 16) acc += y[csr[j]];
#pragma unroll
            for (int o = 8; o; o >>= 1) acc += __shfl_xor(acc, o, 16);
            if (l == 0) {
                float sc = tanhf(acc + b_rel[0] + r[node]);
                scorep[node] = sc;
                keyp[node]   = encodeF(sc);
            }
        }
    }
}

__global__ __launch_bounds__(1024) void radix_p(
    const uint* __restrict__ key, const float* __restrict__ score,
    const float* __restrict__ cvec,
    float* __restrict__ wscp, float* __restrict__ denomp) {
    __shared__ uint  hist[256];
    __shared__ uint  ssum[256];
    __shared__ uint  sh_prefix, sh_need;
    __shared__ float wred[16];
    __shared__ uint  tick_s;
    const int t = threadIdx.x;
    PROBE_LOOP {
        PROBE_FENCE;
        __syncthreads();
        uint prefix = 0, pmask = 0, need = KSEL;
        float vmax = -INFINITY;
        for (int shift = 24; shift >= 0; shift -= 8) {
            if (t < 256) hist[t] = 0;
            __syncthreads();
            if (shift == 0) {
                for (int i = t; i < NN; i += 1024) {
                    uint k = key[i];
                    if ((k & pmask) == prefix) atomicAdd(&hist[k & 255], 1u);
                    if (k >= prefix) vmax = fmaxf(vmax, score[i] * cvec[i]);
                }
            } else {
                for (int i = t; i < NN; i += 1024) {
                    uint k = key[i];
                    if ((k & pmask) == prefix) atomicAdd(&hist[(k >> shift) & 255], 1u);
                }
            }
            __syncthreads();
            if (t < 256) ssum[t] = hist[t];
            __syncthreads();
            for (int off = 1; off < 256; off <<= 1) {
                uint add = 0;
                if (t < 256 && t + off < 256) add = ssum[t + off];
                __syncthreads();
                if (t < 256) ssum[t] += add;
                __syncthreads();
            }
            if (t < 256) {
                uint hi = ssum[t];
                uint lo = (t < 255) ? ssum[t + 1] : 0u;
                if (need <= hi && need > lo) {
                    sh_prefix = prefix | ((uint)t << shift);
                    sh_need   = need - lo;
                }
            }
            __syncthreads();
            prefix = sh_prefix;
            need   = sh_need;
            pmask |= (0xFFu << shift);
            __syncthreads();
        }
        const uint T      = prefix;
        const uint needEq = need;
#pragma unroll
        for (int o = 32; o; o >>= 1) vmax = fmaxf(vmax, __shfl_xor(vmax, o));
        if ((t & 63) == 0) wred[t >> 6] = vmax;
        if (t == 0) tick_s = 0;
        __syncthreads();
        float m = wred[0];
#pragma unroll
        for (int w = 1; w < 16; w++) m = fmaxf(m, wred[w]);
        __syncthreads();
        float dsum = 0.f;
        for (int i = t; i < NN; i += 1024) {
            uint k = key[i];
            bool selm = (k > T);
            if (k == T) selm = (atomicAdd(&tick_s, 1u) < needEq);
            float wv = 0.f;
            if (selm) {
                float s = score[i];
                float w = expf(s * cvec[i] - m);
                wv   = w * s;
                dsum += w;
            }
            wscp[i] = wv;
        }
#pragma unroll
        for (int o = 32; o; o >>= 1) dsum += __shfl_xor(dsum, o);
        if ((t & 63) == 0) wred[t >> 6] = dsum;
        __syncthreads();
        if (t == 0) {
            float d = 0.f;
#pragma unroll
            for (int w = 0; w < 16; w++) d += wred[w];
            denomp[0] = d;
        }
    }
}

__global__ __launch_bounds__(256) void rrows_p(
    const float* __restrict__ x, const float* __restrict__ wsc,
    float* __restrict__ partp, uint* __restrict__ cntp,
    const float* __restrict__ denom, float* __restrict__ outp) {
    __shared__ float red[3][DD];
    __shared__ uint  lastdone;
    const int wave = threadIdx.x >> 6;
    const int lane = threadIdx.x & 63;
    const int row0 = (blockIdx.x * 4 + wave) * 16;
    const float* xp = x + lane * 4;
    PROBE_LOOP {
        PROBE_FENCE;
        __syncthreads();
        float4 acc = make_float4(0.f, 0.f, 0.f, 0.f);
        if (row0 < NN) {
#pragma unroll
            for (int rb = 0; rb < 16; rb += 4) {
                int r0 = row0 + rb;
                float w0 = wsc[r0 + 0], w1 = wsc[r0 + 1];
                float w2 = wsc[r0 + 2], w3 = wsc[r0 + 3];
                float4 v0 = *(const float4*)(xp + (size_t)(r0 + 0) * DD);
                float4 v1 = *(const float4*)(xp + (size_t)(r0 + 1) * DD);
                float4 v2 = *(const float4*)(xp + (size_t)(r0 + 2) * DD);
                float4 v3 = *(const float4*)(xp + (size_t)(r0 + 3) * DD);
                acc.x = fmaf(w0, v0.x, fmaf(w1, v1.x, fmaf(w2, v2.x, fmaf(w3, v3.x, acc.x))));
                acc.y = fmaf(w0, v0.y, fmaf(w1, v1.y, fmaf(w2, v2.y, fmaf(w3, v3.y, acc.y))));
                acc.z = fmaf(w0, v0.z, fmaf(w1, v1.z, fmaf(w2, v2.z, fmaf(w3, v3.z, acc.z))));
                acc.w = fmaf(w0, v0.w, fmaf(w1, v1.w, fmaf(w2, v2.w, fmaf(w3, v3.w, acc.w))));
            }
        }
        if (wave > 0) *(float4*)&red[wave - 1][lane * 4] = acc;
        __syncthreads();
        if (wave == 0) {
#pragma unroll
            for (int w = 0; w < 3; w++) {
                float4 rv = *(float4*)&red[w][lane * 4];
                acc.x += rv.x; acc.y += rv.y; acc.z += rv.z; acc.w += rv.w;
            }
            *(float4*)(partp + (size_t)blockIdx.x * DD + lane * 4) = acc;
        }
        __threadfence();
        if (threadIdx.x == 0) lastdone = atomicAdd(cntp, 1u);
        __syncthreads();
        if (lastdone == NPART - 1) {
            __threadfence();
            int i = threadIdx.x;
            float s = 0.f;
            for (int b = 0; b < NPART; b++) s += partp[(size_t)b * DD + i];
            outp[i] = s / denom[0];
        }
    }
}

extern "C" void kernel_launch(void* const* d_in, const int* in_sizes, int n_in,
                              void* d_out, int out_size, void* d_ws, size_t ws_size,
                              hipStream_t stream) {
    const float* h      = (const float*)d_in[0];
    const int*   ei     = (const int*)d_in[1];
    const float* W_l    = (const float*)d_in[2];
    const float* b_l    = (const float*)d_in[3];
    const float* W_r    = (const float*)d_in[4];
    const float* W_rel  = (const float*)d_in[5];
    const float* b_rel  = (const float*)d_in[6];
    const float* W_root = (const float*)d_in[7];
    const float* W_gate = (const float*)d_in[8];
    float* out = (float*)d_out;

    char* p = (char*)d_ws;
    auto alloc = [&p](size_t bytes) {
        char* q = p;
        p += (bytes + 63) & ~(size_t)63;
        return q;
    };
    // ---- real pipeline buffers ----
    ushort* Ab    = (ushort*)alloc((size_t)NN * KK * 2);
    float*  xbuf  = (float*) alloc((size_t)NN * DD * 4);
    ushort* Wt    = (ushort*)alloc((size_t)DD * KK * 2);
    int*    csr   = (int*)   alloc((size_t)NE * 4);
    int*    start = (int*)   alloc((size_t)(NN + 1) * 4);
    int*    cursor= (int*)   alloc((size_t)NN * 4);
    float*  invdeg= (float*) alloc((size_t)NN * 4);
    float*  score = (float*) alloc((size_t)NN * 4);
    uint*   key   = (uint*)  alloc((size_t)NN * 4);
    float*  wsc   = (float*) alloc((size_t)NN * 4);
    float*  denom = (float*) alloc(64);
    float*  part  = (float*) alloc((size_t)NPART * DD * 4);
    // ---- zero-initialized region (contiguous, 200128 B) ----
    int*    degi  = (int*)   alloc((size_t)NN * 4);
    float*  y     = (float*) alloc((size_t)NN * 4);
    float*  cbuf  = (float*) alloc((size_t)NN * 4);
    float*  rbuf  = (float*) alloc((size_t)NN * 4);
    uint*   cnt   = (uint*)  alloc(64);
    int*    cursorp=(int*)   alloc((size_t)NN * 4);   // probe, must be zeroed
    uint*   cntp  = (uint*)  alloc(64);               // probe, must be zeroed
    // ---- probe scratch (garbage init OK) ----
    ushort* Abp   = (ushort*)alloc((size_t)NN * KK * 2);
    ushort* Wtp   = (ushort*)alloc((size_t)DD * KK * 2);
    int*    startp= (int*)   alloc((size_t)(NN + 1) * 4);
    int*    cursorq=(int*)   alloc((size_t)NN * 4);
    float*  invdegp=(float*) alloc((size_t)NN * 4);
    int*    csr2  = (int*)   alloc((size_t)NE * 4);
    float*  xbufp = (float*) alloc((size_t)NN * DD * 4);
    float*  yp    = (float*) alloc((size_t)NN * 4);
    float*  cp    = (float*) alloc((size_t)NN * 4);
    float*  rp    = (float*) alloc((size_t)NN * 4);
    float*  scorep= (float*) alloc((size_t)NN * 4);
    uint*   keyp  = (uint*)  alloc((size_t)NN * 4);
    float*  wscp  = (float*) alloc((size_t)NN * 4);
    float*  denomp= (float*) alloc(64);
    float*  partp = (float*) alloc((size_t)NPART * DD * 4);
    float*  outp  = (float*) alloc(DD * 4);

    // ---------------- real pipeline (unchanged semantics) ----------------
    zero_bufs   <<<(ZQUADS + 255) / 256, 256, 0, stream>>>((float4*)degi);
    prep        <<<WB + HB + DB, 256, 0, stream>>>(h, W_l, W_r, ei, Ab, Wt, degi);
    scan_start  <<<1, 1024, 0, stream>>>(degi, start, cursor, invdeg);
    fill_csr    <<<(NE + 255) / 256, 256, 0, stream>>>(ei, cursor, csr);
    gather_mean <<<(NN + 3) / 4, 256, 0, stream>>>(Ab, csr, start, invdeg);
    gemm_x      <<<(NN + 31) / 32, 256, 0, stream>>>(Ab, Wt, b_l,
                                                     W_rel, W_gate, W_root,
                                                     xbuf, y, cbuf, rbuf);
    gather_score<<<(NN * 16 + 255) / 256, 256, 0, stream>>>(y, rbuf, b_rel, csr,
                                                            start, score, key);
    radix_select<<<1, 1024, 0, stream>>>(key, score, cbuf, wsc, denom);
    reduce_rows <<<NPART, 256, 0, stream>>>(xbuf, wsc, part, cnt, denom, out);

    // ---------------- probes: x16 each, scratch outputs ------------------
    prep_p   <<<WB + HB + DB, 256, 0, stream>>>(h, W_l, W_r, ei, Abp, Wtp, degi);
    scan_p   <<<1, 1024, 0, stream>>>(degi, startp, cursorq, invdegp);
    fillcsr_p<<<(NE + 255) / 256, 256, 0, stream>>>(ei, cursorp, start, csr2);
    gmean_p  <<<(NN + 3) / 4, 256, 0, stream>>>(Ab, Abp, csr, start, invdeg);
    gemm_p   <<<(NN + 31) / 32, 256, 0, stream>>>(Ab, Wt, b_l, W_rel, W_gate,
                                                  W_root, xbufp, yp, cp, rp);
    gscore_p <<<(NN * 16 + 255) / 256, 256, 0, stream>>>(y, rbuf, b_rel, csr,
                                                         start, scorep, keyp);
    radix_p  <<<1, 1024, 0, stream>>>(key, score, cbuf, wscp, denomp);
    rrows_p  <<<NPART, 256, 0, stream>>>(xbuf, wsc, partp, cntp, denom, outp);
    (void)n_in; (void)in_sizes; (void)out_size; (void)ws_size;
}

// Round 12
// 172.689 us; speedup vs baseline: 13.5864x; 13.5864x over previous
//
#include <hip/hip_runtime.h>
#include <math.h>

#define NN 10000
#define NE 320000
#define DD 256
#define KSEL 8000
#define KK 512
#define NPART 157

typedef unsigned int uint;
typedef unsigned short ushort;
typedef __attribute__((ext_vector_type(8))) short short8;
typedef __attribute__((ext_vector_type(4))) float f32x4;
typedef __attribute__((ext_vector_type(4))) ushort us4;
typedef __attribute__((ext_vector_type(8))) ushort us8;

__device__ __forceinline__ uint encodeF(float f) {
    uint u = __float_as_uint(f);
    return (u & 0x80000000u) ? ~u : (u | 0x80000000u);
}

__device__ __forceinline__ ushort f2bf(float f) {
    uint u = __float_as_uint(f);
    u += 0x7FFFu + ((u >> 16) & 1u);
    return (ushort)(u >> 16);
}

// ---------------- 0. zero degi + cnt (contiguous 40064 B) -----------------
#define ZQUADS 2504
__global__ __launch_bounds__(256) void zero_bufs(float4* __restrict__ z) {
    int i = blockIdx.x * 256 + threadIdx.x;
    if (i < ZQUADS) z[i] = make_float4(0.f, 0.f, 0.f, 0.f);
}

// ---------------- 1. prep: W-transpose + cast_h + count_deg ---------------
#define WB 32
#define HB 2500
#define DB 1250
__global__ __launch_bounds__(256) void prep(
    const float* __restrict__ h, const float* __restrict__ W_l,
    const float* __restrict__ W_r, const int* __restrict__ ei,
    ushort* __restrict__ Ab, ushort* __restrict__ Wt,
    int* __restrict__ degi) {
    const int b = blockIdx.x, t = threadIdx.x;
    if (b < WB) {
        __shared__ float tile[64][65];
        const int tr = b >> 2, tc = b & 3;
        const int k0 = tr * 64, n0 = tc * 64;
        const int r = t >> 6, c = t & 63;
        const float* Wsrc = (k0 < 256) ? (W_l + (size_t)k0 * DD)
                                       : (W_r + (size_t)(k0 - 256) * DD);
#pragma unroll
        for (int i = 0; i < 16; i++) {
            int row = r + i * 4;
            tile[row][c] = Wsrc[(size_t)row * DD + n0 + c];
        }
        __syncthreads();
#pragma unroll
        for (int i = 0; i < 16; i++) {
            int row = r + i * 4;
            Wt[(size_t)(n0 + row) * KK + k0 + c] = f2bf(tile[c][row]);
        }
    } else if (b < WB + HB) {
        int id = (b - WB) * 256 + t;
        int node = id >> 6, seg = (id & 63) * 4;
        float4 v = *(const float4*)(h + (size_t)node * DD + seg);
        us4 o;
        o[0] = f2bf(v.x); o[1] = f2bf(v.y); o[2] = f2bf(v.z); o[3] = f2bf(v.w);
        *(us4*)(Ab + (size_t)node * KK + 256 + seg) = o;
    } else {
        int e = (b - WB - HB) * 256 + t;
        if (e < NE) atomicAdd(&degi[ei[NE + e]], 1);
    }
}

// ---------------- 2. prefix scan (shuffle-based, 2 syncs) -----------------
__global__ __launch_bounds__(1024) void scan_start(
    const int* __restrict__ degi, int* __restrict__ start,
    int* __restrict__ cursor, float* __restrict__ invdeg) {
    __shared__ int wsum[16];
    __shared__ int woff[16];
    const int t = threadIdx.x, wid = t >> 6, lane = t & 63;
    const int CH = 10;
    const int base = t * CH;
    int sum = 0;
#pragma unroll
    for (int i = 0; i < CH; i++) {
        int idx = base + i;
        if (idx < NN) sum += degi[idx];
    }
    int x = sum;                              // in-wave inclusive scan
#pragma unroll
    for (int off = 1; off < 64; off <<= 1) {
        int v = __shfl_up(x, off);
        if (lane >= off) x += v;
    }
    if (lane == 63) wsum[wid] = x;
    __syncthreads();
    if (t == 0) {
        int run = 0;
#pragma unroll
        for (int w = 0; w < 16; w++) { woff[w] = run; run += wsum[w]; }
    }
    __syncthreads();
    int run = woff[wid] + x - sum;            // exclusive prefix
#pragma unroll
    for (int i = 0; i < CH; i++) {
        int idx = base + i;
        if (idx < NN) {
            start[idx]  = run;
            cursor[idx] = run;
            int d = degi[idx];
            invdeg[idx] = 1.0f / fmaxf((float)d, 1.0f);
            run += d;
        }
    }
    if (t == 1023) start[NN] = NE;
}

// ---------------- 3. fill CSR ---------------------------------------------
__global__ __launch_bounds__(256) void fill_csr(
    const int* __restrict__ ei, int* __restrict__ cursor,
    int* __restrict__ csr) {
    int e = blockIdx.x * 256 + threadIdx.x;
    if (e >= NE) return;
    int pos = atomicAdd(&cursor[ei[NE + e]], 1);
    csr[pos] = ei[e];
}

// ---------------- 4. gather mean ------------------------------------------
__global__ __launch_bounds__(256) void gather_mean(
    ushort* __restrict__ Ab, const int* __restrict__ csr,
    const int* __restrict__ start, const float* __restrict__ invdeg) {
    int node = blockIdx.x * 4 + (threadIdx.x >> 6);
    int lane = threadIdx.x & 63;
    if (node >= NN) return;
    int s = start[node], e = start[node + 1];
    const ushort* hb = Ab + 256 + lane * 4;
    float4 A0 = make_float4(0.f, 0.f, 0.f, 0.f);
    float4 A1 = make_float4(0.f, 0.f, 0.f, 0.f);
    int j = s;
    for (; j + 2 <= e; j += 2) {
        int s0 = csr[j], s1 = csr[j + 1];
        uint2 v0 = *(const uint2*)(hb + (size_t)s0 * KK);
        uint2 v1 = *(const uint2*)(hb + (size_t)s1 * KK);
        A0.x += __uint_as_float(v0.x << 16);
        A0.y += __uint_as_float(v0.x & 0xFFFF0000u);
        A0.z += __uint_as_float(v0.y << 16);
        A0.w += __uint_as_float(v0.y & 0xFFFF0000u);
        A1.x += __uint_as_float(v1.x << 16);
        A1.y += __uint_as_float(v1.x & 0xFFFF0000u);
        A1.z += __uint_as_float(v1.y << 16);
        A1.w += __uint_as_float(v1.y & 0xFFFF0000u);
    }
    for (; j < e; j++) {
        uint2 v0 = *(const uint2*)(hb + (size_t)csr[j] * KK);
        A0.x += __uint_as_float(v0.x << 16);
        A0.y += __uint_as_float(v0.x & 0xFFFF0000u);
        A0.z += __uint_as_float(v0.y << 16);
        A0.w += __uint_as_float(v0.y & 0xFFFF0000u);
    }
    float id = invdeg[node];
    us4 m;
    m[0] = f2bf((A0.x + A1.x) * id);
    m[1] = f2bf((A0.y + A1.y) * id);
    m[2] = f2bf((A0.z + A1.z) * id);
    m[3] = f2bf((A0.w + A1.w) * id);
    *(us4*)(Ab + (size_t)node * KK + lane * 4) = m;
}

// ---------------- 5. MFMA GEMM: atomic-free y/c/r via LDS reduce ----------
__global__ __launch_bounds__(256) void gemm_x(
    const ushort* __restrict__ Ab, const ushort* __restrict__ Wt,
    const float* __restrict__ b_l,
    const float* __restrict__ W_rel, const float* __restrict__ W_gate,
    const float* __restrict__ W_root,
    float* __restrict__ xout, float* __restrict__ y,
    float* __restrict__ cvec, float* __restrict__ rvec) {
    __shared__ ushort Asm[2][32][40];
    __shared__ ushort Bsm[2][256][40];
    __shared__ float Ys[4][32], Cs[4][32], Rs[4][32];
    const int t    = threadIdx.x;
    const int row0 = blockIdx.x * 32;
    const int wid  = t >> 6, lane = t & 63;
    const int l15  = lane & 15, g = lane >> 4;

    f32x4 acc[2][4];
#pragma unroll
    for (int fi = 0; fi < 2; fi++)
#pragma unroll
        for (int fj = 0; fj < 4; fj++) acc[fi][fj] = (f32x4)0.f;

    const int  arow = t >> 3, akseg = (t & 7) * 4;
    const bool aok  = (row0 + arow) < NN;
    const ushort* aptr = Ab + (size_t)(row0 + arow) * KK + akseg;
    const ushort* bptr = Wt + (size_t)t * KK;

    us4 areg = {0, 0, 0, 0};
    us8 breg[4];
    if (aok) areg = *(const us4*)(aptr);
#pragma unroll
    for (int jj = 0; jj < 4; jj++) breg[jj] = *(const us8*)(bptr + jj * 8);
    *(us4*)&Asm[0][arow][akseg] = areg;
#pragma unroll
    for (int jj = 0; jj < 4; jj++) *(us8*)&Bsm[0][t][jj * 8] = breg[jj];
    __syncthreads();

    for (int ks = 0; ks < 16; ++ks) {
        const int cur = ks & 1;
        if (ks < 15) {
            const int k0 = (ks + 1) * 32;
            if (aok) areg = *(const us4*)(aptr + k0);
#pragma unroll
            for (int jj = 0; jj < 4; jj++) breg[jj] = *(const us8*)(bptr + k0 + jj * 8);
        }
        short8 af0 = *(const short8*)&Asm[cur][l15][g * 8];
        short8 af1 = *(const short8*)&Asm[cur][16 + l15][g * 8];
#pragma unroll
        for (int fj = 0; fj < 4; fj++) {
            short8 bf = *(const short8*)&Bsm[cur][wid * 64 + fj * 16 + l15][g * 8];
            acc[0][fj] = __builtin_amdgcn_mfma_f32_16x16x32_bf16(af0, bf, acc[0][fj], 0, 0, 0);
            acc[1][fj] = __builtin_amdgcn_mfma_f32_16x16x32_bf16(af1, bf, acc[1][fj], 0, 0, 0);
        }
        if (ks < 15) {
            const int nb = cur ^ 1;
            *(us4*)&Asm[nb][arow][akseg] = areg;
#pragma unroll
            for (int jj = 0; jj < 4; jj++) *(us8*)&Bsm[nb][t][jj * 8] = breg[jj];
        }
        __syncthreads();
    }

    const int wcol0 = wid * 64;
    float bl[4], wl[4], wg[4], wo[4];
#pragma unroll
    for (int fj = 0; fj < 4; fj++) {
        int col = wcol0 + fj * 16 + l15;
        bl[fj] = b_l[col]; wl[fj] = W_rel[col];
        wg[fj] = W_gate[col]; wo[fj] = W_root[col];
    }
#pragma unroll
    for (int fi = 0; fi < 2; fi++) {
#pragma unroll
        for (int r = 0; r < 4; r++) {
            int row = row0 + fi * 16 + g * 4 + r;
            float py = 0.f, pc = 0.f, pr = 0.f;
#pragma unroll
            for (int fj = 0; fj < 4; fj++) {
                float v = fmaxf(acc[fi][fj][r] + bl[fj], 0.f);
                if (row < NN)
                    xout[(size_t)row * DD + wcol0 + fj * 16 + l15] = v;
                py = fmaf(v, wl[fj], py);
                pc = fmaf(v, wg[fj], pc);
                pr = fmaf(v, wo[fj], pr);
            }
#pragma unroll
            for (int off = 1; off < 16; off <<= 1) {
                py += __shfl_xor(py, off);
                pc += __shfl_xor(pc, off);
                pr += __shfl_xor(pr, off);
            }
            if (l15 == 0) {
                int rl = fi * 16 + g * 4 + r;
                Ys[wid][rl] = py; Cs[wid][rl] = pc; Rs[wid][rl] = pr;
            }
        }
    }
    __syncthreads();
    if (t < 32) {                  // cross-wave reduce, plain stores (no atomics)
        int row = row0 + t;
        if (row < NN) {
            y[row]    = Ys[0][t] + Ys[1][t] + Ys[2][t] + Ys[3][t];
            cvec[row] = Cs[0][t] + Cs[1][t] + Cs[2][t] + Cs[3][t];
            rvec[row] = Rs[0][t] + Rs[1][t] + Rs[2][t] + Rs[3][t];
        }
    }
}

// ---------------- 6. gather y + score + key -------------------------------
__global__ __launch_bounds__(256) void gather_score(
    const float* __restrict__ y, const float* __restrict__ r,
    const float* __restrict__ b_rel, const int* __restrict__ csr,
    const int* __restrict__ start,
    float* __restrict__ score, uint* __restrict__ key) {
    int gt   = blockIdx.x * 256 + threadIdx.x;
    int node = gt >> 4, l = gt & 15;
    if (node >= NN) return;
    int s = start[node], e = start[node + 1];
    float acc = 0.f;
    for (int j = s + l; j < e; j += 16) acc += y[csr[j]];
#pragma unroll
    for (int o = 8; o; o >>= 1) acc += __shfl_xor(acc, o, 16);
    if (l == 0) {
        float sc = tanhf(acc + b_rel[0] + r[node]);
        score[node] = sc;
        key[node]   = encodeF(sc);
    }
}

// ---------------- 7. radix select v2: reg-preload + wave-private hists ----
// 10 keys/thread in regs; hist[16][260] (wave-private, bank-shifted);
// wave-0 shuffle suffix-scan; 2 syncs per pass.
__global__ __launch_bounds__(1024) void radix_select(
    const uint* __restrict__ key, const float* __restrict__ score,
    const float* __restrict__ cvec,
    float* __restrict__ wsc, float* __restrict__ denom) {
    __shared__ uint  hist[16][260];   // 260: 16B-aligned rows, bank-shift 4/wid
    __shared__ uint  sh_prefix, sh_need;
    __shared__ float wred[16];
    __shared__ uint  tick_s;
    const int t = threadIdx.x, wid = t >> 6, lane = t & 63;

    uint  myk[10];
    float mys[10], myl[10];
#pragma unroll
    for (int i = 0; i < 10; i++) {
        int idx = t + i * 1024;
        if (idx < NN) {
            uint k  = key[idx];
            float s = score[idx];
            myk[i] = k; mys[i] = s; myl[i] = s * cvec[idx];
        } else {
            myk[i] = 0u; mys[i] = 0.f; myl[i] = -INFINITY;  // phantom: smallest key
        }
    }

    uint prefix = 0, pmask = 0, need = KSEL;
    float vmax = -INFINITY;
    for (int shift = 24; shift >= 0; shift -= 8) {
        for (int i = lane; i < 256; i += 64) hist[wid][i] = 0;  // wave-private
        if (shift == 0) {
#pragma unroll
            for (int i = 0; i < 10; i++) {
                uint k = myk[i];
                if ((k & pmask) == prefix) atomicAdd(&hist[wid][k & 255], 1u);
                if (k >= prefix) vmax = fmaxf(vmax, myl[i]);   // superset max
            }
        } else {
#pragma unroll
            for (int i = 0; i < 10; i++) {
                uint k = myk[i];
                if ((k & pmask) == prefix)
                    atomicAdd(&hist[wid][(k >> shift) & 255], 1u);
            }
        }
        __syncthreads();
        if (wid == 0) {                       // reduce 16 copies + suffix scan
            uint4 a = make_uint4(0u, 0u, 0u, 0u);
#pragma unroll
            for (int w = 0; w < 16; w++) {
                uint4 v = *(const uint4*)&hist[w][lane * 4];
                a.x += v.x; a.y += v.y; a.z += v.z; a.w += v.w;
            }
            uint s3 = a.w, s2 = a.z + s3, s1 = a.y + s2, s0 = a.x + s1;
            uint x = s0;                      // inclusive lane suffix of totals
#pragma unroll
            for (int off = 1; off < 64; off <<= 1) {
                uint v = __shfl_down(x, off);
                if (lane + off < 64) x += v;
            }
            uint excl = x - s0;               // strictly-above-lane total
            uint hi0 = excl + s0, hi1 = excl + s1;
            uint hi2 = excl + s2, hi3 = excl + s3;
            if (need <= hi0 && need > hi0 - a.x) {
                sh_prefix = prefix | ((uint)(lane * 4 + 0) << shift);
                sh_need   = need - (hi0 - a.x);
            }
            if (need <= hi1 && need > hi1 - a.y) {
                sh_prefix = prefix | ((uint)(lane * 4 + 1) << shift);
                sh_need   = need - (hi1 - a.y);
            }
            if (need <= hi2 && need > hi2 - a.z) {
                sh_prefix = prefix | ((uint)(lane * 4 + 2) << shift);
                sh_need   = need - (hi2 - a.z);
            }
            if (need <= hi3 && need > hi3 - a.w) {
                sh_prefix = prefix | ((uint)(lane * 4 + 3) << shift);
                sh_need   = need - (hi3 - a.w);
            }
        }
        __syncthreads();
        prefix = sh_prefix;
        need   = sh_need;
        pmask |= (0xFFu << shift);
    }
    const uint T      = prefix;
    const uint needEq = need;
    // ---- reduce vmax -> m ----
#pragma unroll
    for (int o = 32; o; o >>= 1) vmax = fmaxf(vmax, __shfl_xor(vmax, o));
    if (lane == 0) wred[wid] = vmax;
    if (t == 0) tick_s = 0;
    __syncthreads();
    float m = wred[0];
#pragma unroll
    for (int w = 1; w < 16; w++) m = fmaxf(m, wred[w]);
    __syncthreads();                          // all read wred before reuse
    // ---- dense weights + denom ----
    float dsum = 0.f;
#pragma unroll
    for (int i = 0; i < 10; i++) {
        int idx = t + i * 1024;
        if (idx >= NN) continue;
        uint k = myk[i];
        bool selm = (k > T);
        if (k == T) selm = (atomicAdd(&tick_s, 1u) < needEq);
        float wv = 0.f;
        if (selm) {
            float w = expf(myl[i] - m);
            wv   = w * mys[i];
            dsum += w;
        }
        wsc[idx] = wv;
    }
#pragma unroll
    for (int o = 32; o; o >>= 1) dsum += __shfl_xor(dsum, o);
    if (lane == 0) wred[wid] = dsum;
    __syncthreads();
    if (t == 0) {
        float d = 0.f;
#pragma unroll
        for (int w = 0; w < 16; w++) d += wred[w];
        denom[0] = d;
    }
}

// ---------------- 8. weighted row-sum + last-block finalize ---------------
__global__ __launch_bounds__(256) void reduce_rows(
    const float* __restrict__ x, const float* __restrict__ wsc,
    float* __restrict__ part, uint* __restrict__ counter,
    const float* __restrict__ denom, float* __restrict__ out) {
    __shared__ float red[3][DD];
    __shared__ uint  lastdone;
    const int wave = threadIdx.x >> 6;
    const int lane = threadIdx.x & 63;
    const int row0 = (blockIdx.x * 4 + wave) * 16;
    const float* xp = x + lane * 4;
    float4 acc = make_float4(0.f, 0.f, 0.f, 0.f);
    if (row0 < NN) {
#pragma unroll
        for (int rb = 0; rb < 16; rb += 4) {
            int r0 = row0 + rb;
            float w0 = wsc[r0 + 0], w1 = wsc[r0 + 1];
            float w2 = wsc[r0 + 2], w3 = wsc[r0 + 3];
            float4 v0 = *(const float4*)(xp + (size_t)(r0 + 0) * DD);
            float4 v1 = *(const float4*)(xp + (size_t)(r0 + 1) * DD);
            float4 v2 = *(const float4*)(xp + (size_t)(r0 + 2) * DD);
            float4 v3 = *(const float4*)(xp + (size_t)(r0 + 3) * DD);
            acc.x = fmaf(w0, v0.x, fmaf(w1, v1.x, fmaf(w2, v2.x, fmaf(w3, v3.x, acc.x))));
            acc.y = fmaf(w0, v0.y, fmaf(w1, v1.y, fmaf(w2, v2.y, fmaf(w3, v3.y, acc.y))));
            acc.z = fmaf(w0, v0.z, fmaf(w1, v1.z, fmaf(w2, v2.z, fmaf(w3, v3.z, acc.z))));
            acc.w = fmaf(w0, v0.w, fmaf(w1, v1.w, fmaf(w2, v2.w, fmaf(w3, v3.w, acc.w))));
        }
    }
    if (wave > 0) *(float4*)&red[wave - 1][lane * 4] = acc;
    __syncthreads();
    if (wave == 0) {
#pragma unroll
        for (int w = 0; w < 3; w++) {
            float4 rv = *(float4*)&red[w][lane * 4];
            acc.x += rv.x; acc.y += rv.y; acc.z += rv.z; acc.w += rv.w;
        }
        *(float4*)(part + (size_t)blockIdx.x * DD + lane * 4) = acc;
    }
    __threadfence();
    if (threadIdx.x == 0) lastdone = atomicAdd(counter, 1u);
    __syncthreads();
    if (lastdone == NPART - 1) {
        __threadfence();
        int i = threadIdx.x;
        float s = 0.f;
        for (int b = 0; b < NPART; b++) s += part[(size_t)b * DD + i];
        out[i] = s / denom[0];
    }
}

extern "C" void kernel_launch(void* const* d_in, const int* in_sizes, int n_in,
                              void* d_out, int out_size, void* d_ws, size_t ws_size,
                              hipStream_t stream) {
    const float* h      = (const float*)d_in[0];
    const int*   ei     = (const int*)d_in[1];
    const float* W_l    = (const float*)d_in[2];
    const float* b_l    = (const float*)d_in[3];
    const float* W_r    = (const float*)d_in[4];
    const float* W_rel  = (const float*)d_in[5];
    const float* b_rel  = (const float*)d_in[6];
    const float* W_root = (const float*)d_in[7];
    const float* W_gate = (const float*)d_in[8];
    // b_gate (d_in[9]) cancels in softmax
    float* out = (float*)d_out;

    char* p = (char*)d_ws;
    auto alloc = [&p](size_t bytes) {
        char* q = p;
        p += (bytes + 63) & ~(size_t)63;
        return q;
    };
    ushort* Ab    = (ushort*)alloc((size_t)NN * KK * 2);
    float*  xbuf  = (float*) alloc((size_t)NN * DD * 4);
    ushort* Wt    = (ushort*)alloc((size_t)DD * KK * 2);
    int*    csr   = (int*)   alloc((size_t)NE * 4);
    int*    start = (int*)   alloc((size_t)(NN + 1) * 4);
    int*    cursor= (int*)   alloc((size_t)NN * 4);
    float*  invdeg= (float*) alloc((size_t)NN * 4);
    float*  score = (float*) alloc((size_t)NN * 4);
    uint*   key   = (uint*)  alloc((size_t)NN * 4);
    float*  wsc   = (float*) alloc((size_t)NN * 4);
    float*  denom = (float*) alloc(64);
    float*  part  = (float*) alloc((size_t)NPART * DD * 4);
    float*  y     = (float*) alloc((size_t)NN * 4);    // fully written by gemm
    float*  cbuf  = (float*) alloc((size_t)NN * 4);    // fully written by gemm
    float*  rbuf  = (float*) alloc((size_t)NN * 4);    // fully written by gemm
    // ---- zero-initialized region (contiguous, 40064 B) ----
    int*    degi  = (int*)   alloc((size_t)NN * 4);
    uint*   cnt   = (uint*)  alloc(64);

    zero_bufs   <<<(ZQUADS + 255) / 256, 256, 0, stream>>>((float4*)degi);
    prep        <<<WB + HB + DB, 256, 0, stream>>>(h, W_l, W_r, ei, Ab, Wt, degi);
    scan_start  <<<1, 1024, 0, stream>>>(degi, start, cursor, invdeg);
    fill_csr    <<<(NE + 255) / 256, 256, 0, stream>>>(ei, cursor, csr);
    gather_mean <<<(NN + 3) / 4, 256, 0, stream>>>(Ab, csr, start, invdeg);
    gemm_x      <<<(NN + 31) / 32, 256, 0, stream>>>(Ab, Wt, b_l,
                                                     W_rel, W_gate, W_root,
                                                     xbuf, y, cbuf, rbuf);
    gather_score<<<(NN * 16 + 255) / 256, 256, 0, stream>>>(y, rbuf, b_rel, csr,
                                                            start, score, key);
    radix_select<<<1, 1024, 0, stream>>>(key, score, cbuf, wsc, denom);
    reduce_rows <<<NPART, 256, 0, stream>>>(xbuf, wsc, part, cnt, denom, out);
    (void)n_in; (void)in_sizes; (void)out_size; (void)ws_size;
}

// Round 13
// 161.304 us; speedup vs baseline: 14.5454x; 1.0706x over previous
//
#include <hip/hip_runtime.h>
#include <hip/hip_fp8.h>
#include <math.h>

#define NN 10000
#define NE 320000
#define DD 256
#define KSEL 8000
#define KK 512
#define NPART 157

typedef unsigned int uint;
typedef unsigned short ushort;
typedef unsigned char uchar;
typedef __attribute__((ext_vector_type(8))) short short8;
typedef __attribute__((ext_vector_type(4))) float f32x4;
typedef __attribute__((ext_vector_type(4))) ushort us4;
typedef __attribute__((ext_vector_type(8))) ushort us8;

__device__ __forceinline__ uint encodeF(float f) {
    uint u = __float_as_uint(f);
    return (u & 0x80000000u) ? ~u : (u | 0x80000000u);
}

__device__ __forceinline__ ushort f2bf(float f) {
    uint u = __float_as_uint(f);
    u += 0x7FFFu + ((u >> 16) & 1u);
    return (ushort)(u >> 16);
}

__device__ __forceinline__ float fp8dec(uint b) {
    __hip_fp8_e4m3 t;
    t.__x = (__hip_fp8_storage_t)b;
    return (float)t;
}
__device__ __forceinline__ uint fp8enc(float f) {
    return (uint)__hip_fp8_e4m3(f).__x;
}

// ---------------- 0. zero degi + cnt (contiguous 40064 B) -----------------
#define ZQUADS 2504
__global__ __launch_bounds__(256) void zero_bufs(float4* __restrict__ z) {
    int i = blockIdx.x * 256 + threadIdx.x;
    if (i < ZQUADS) z[i] = make_float4(0.f, 0.f, 0.f, 0.f);
}

// ---------------- 1. prep: W-transpose + cast_h (bf16 + fp8) + count ------
#define WB 32
#define HB 2500
#define DB 1250
__global__ __launch_bounds__(256) void prep(
    const float* __restrict__ h, const float* __restrict__ W_l,
    const float* __restrict__ W_r, const int* __restrict__ ei,
    ushort* __restrict__ Ab, uchar* __restrict__ h8,
    ushort* __restrict__ Wt, int* __restrict__ degi) {
    const int b = blockIdx.x, t = threadIdx.x;
    if (b < WB) {
        __shared__ float tile[64][65];
        const int tr = b >> 2, tc = b & 3;
        const int k0 = tr * 64, n0 = tc * 64;
        const int r = t >> 6, c = t & 63;
        const float* Wsrc = (k0 < 256) ? (W_l + (size_t)k0 * DD)
                                       : (W_r + (size_t)(k0 - 256) * DD);
#pragma unroll
        for (int i = 0; i < 16; i++) {
            int row = r + i * 4;
            tile[row][c] = Wsrc[(size_t)row * DD + n0 + c];
        }
        __syncthreads();
#pragma unroll
        for (int i = 0; i < 16; i++) {
            int row = r + i * 4;
            Wt[(size_t)(n0 + row) * KK + k0 + c] = f2bf(tile[c][row]);
        }
    } else if (b < WB + HB) {
        int id = (b - WB) * 256 + t;
        int node = id >> 6, seg = (id & 63) * 4;
        float4 v = *(const float4*)(h + (size_t)node * DD + seg);
        us4 o;
        o[0] = f2bf(v.x); o[1] = f2bf(v.y); o[2] = f2bf(v.z); o[3] = f2bf(v.w);
        *(us4*)(Ab + (size_t)node * KK + 256 + seg) = o;
        uint pk = fp8enc(v.x) | (fp8enc(v.y) << 8)
                | (fp8enc(v.z) << 16) | (fp8enc(v.w) << 24);
        *(uint*)(h8 + (size_t)node * DD + seg) = pk;
    } else {
        int e = (b - WB - HB) * 256 + t;
        if (e < NE) atomicAdd(&degi[ei[NE + e]], 1);
    }
}

// ---------------- 2. prefix scan (shuffle-based, 2 syncs) -----------------
__global__ __launch_bounds__(1024) void scan_start(
    const int* __restrict__ degi, int* __restrict__ start,
    int* __restrict__ cursor, float* __restrict__ invdeg) {
    __shared__ int wsum[16];
    __shared__ int woff[16];
    const int t = threadIdx.x, wid = t >> 6, lane = t & 63;
    const int CH = 10;
    const int base = t * CH;
    int sum = 0;
#pragma unroll
    for (int i = 0; i < CH; i++) {
        int idx = base + i;
        if (idx < NN) sum += degi[idx];
    }
    int x = sum;
#pragma unroll
    for (int off = 1; off < 64; off <<= 1) {
        int v = __shfl_up(x, off);
        if (lane >= off) x += v;
    }
    if (lane == 63) wsum[wid] = x;
    __syncthreads();
    if (t == 0) {
        int run = 0;
#pragma unroll
        for (int w = 0; w < 16; w++) { woff[w] = run; run += wsum[w]; }
    }
    __syncthreads();
    int run = woff[wid] + x - sum;
#pragma unroll
    for (int i = 0; i < CH; i++) {
        int idx = base + i;
        if (idx < NN) {
            start[idx]  = run;
            cursor[idx] = run;
            int d = degi[idx];
            invdeg[idx] = 1.0f / fmaxf((float)d, 1.0f);
            run += d;
        }
    }
    if (t == 1023) start[NN] = NE;
}

// ---------------- 3. fill CSR ---------------------------------------------
__global__ __launch_bounds__(256) void fill_csr(
    const int* __restrict__ ei, int* __restrict__ cursor,
    int* __restrict__ csr) {
    int e = blockIdx.x * 256 + threadIdx.x;
    if (e >= NE) return;
    int pos = atomicAdd(&cursor[ei[NE + e]], 1);
    csr[pos] = ei[e];
}

// ---------------- 4. gather mean (fp8 reads: 256B/edge, L2-resident) ------
__global__ __launch_bounds__(256) void gather_mean(
    ushort* __restrict__ Ab, const uchar* __restrict__ h8,
    const int* __restrict__ csr,
    const int* __restrict__ start, const float* __restrict__ invdeg) {
    int node = blockIdx.x * 4 + (threadIdx.x >> 6);
    int lane = threadIdx.x & 63;
    if (node >= NN) return;
    int s = start[node], e = start[node + 1];
    const uchar* hp = h8 + lane * 4;
    float a0 = 0.f, a1 = 0.f, a2 = 0.f, a3 = 0.f;
    float b0 = 0.f, b1 = 0.f, b2 = 0.f, b3 = 0.f;
    int j = s;
    for (; j + 4 <= e; j += 4) {
        int s0 = csr[j], s1 = csr[j + 1], s2 = csr[j + 2], s3 = csr[j + 3];
        uint w0 = *(const uint*)(hp + (size_t)s0 * DD);
        uint w1 = *(const uint*)(hp + (size_t)s1 * DD);
        uint w2 = *(const uint*)(hp + (size_t)s2 * DD);
        uint w3 = *(const uint*)(hp + (size_t)s3 * DD);
        a0 += fp8dec(w0 & 0xFF) + fp8dec(w1 & 0xFF);
        a1 += fp8dec((w0 >> 8) & 0xFF) + fp8dec((w1 >> 8) & 0xFF);
        a2 += fp8dec((w0 >> 16) & 0xFF) + fp8dec((w1 >> 16) & 0xFF);
        a3 += fp8dec(w0 >> 24) + fp8dec(w1 >> 24);
        b0 += fp8dec(w2 & 0xFF) + fp8dec(w3 & 0xFF);
        b1 += fp8dec((w2 >> 8) & 0xFF) + fp8dec((w3 >> 8) & 0xFF);
        b2 += fp8dec((w2 >> 16) & 0xFF) + fp8dec((w3 >> 16) & 0xFF);
        b3 += fp8dec(w2 >> 24) + fp8dec(w3 >> 24);
    }
    for (; j < e; j++) {
        uint w0 = *(const uint*)(hp + (size_t)csr[j] * DD);
        a0 += fp8dec(w0 & 0xFF);
        a1 += fp8dec((w0 >> 8) & 0xFF);
        a2 += fp8dec((w0 >> 16) & 0xFF);
        a3 += fp8dec(w0 >> 24);
    }
    float id = invdeg[node];
    us4 m;
    m[0] = f2bf((a0 + b0) * id);
    m[1] = f2bf((a1 + b1) * id);
    m[2] = f2bf((a2 + b2) * id);
    m[3] = f2bf((a3 + b3) * id);
    *(us4*)(Ab + (size_t)node * KK + lane * 4) = m;
}

// ---------------- 5. MFMA GEMM: atomic-free y/c/r via LDS reduce ----------
__global__ __launch_bounds__(256) void gemm_x(
    const ushort* __restrict__ Ab, const ushort* __restrict__ Wt,
    const float* __restrict__ b_l,
    const float* __restrict__ W_rel, const float* __restrict__ W_gate,
    const float* __restrict__ W_root,
    float* __restrict__ xout, float* __restrict__ y,
    float* __restrict__ cvec, float* __restrict__ rvec) {
    __shared__ ushort Asm[2][32][40];
    __shared__ ushort Bsm[2][256][40];
    __shared__ float Ys[4][32], Cs[4][32], Rs[4][32];
    const int t    = threadIdx.x;
    const int row0 = blockIdx.x * 32;
    const int wid  = t >> 6, lane = t & 63;
    const int l15  = lane & 15, g = lane >> 4;

    f32x4 acc[2][4];
#pragma unroll
    for (int fi = 0; fi < 2; fi++)
#pragma unroll
        for (int fj = 0; fj < 4; fj++) acc[fi][fj] = (f32x4)0.f;

    const int  arow = t >> 3, akseg = (t & 7) * 4;
    const bool aok  = (row0 + arow) < NN;
    const ushort* aptr = Ab + (size_t)(row0 + arow) * KK + akseg;
    const ushort* bptr = Wt + (size_t)t * KK;

    us4 areg = {0, 0, 0, 0};
    us8 breg[4];
    if (aok) areg = *(const us4*)(aptr);
#pragma unroll
    for (int jj = 0; jj < 4; jj++) breg[jj] = *(const us8*)(bptr + jj * 8);
    *(us4*)&Asm[0][arow][akseg] = areg;
#pragma unroll
    for (int jj = 0; jj < 4; jj++) *(us8*)&Bsm[0][t][jj * 8] = breg[jj];
    __syncthreads();

    for (int ks = 0; ks < 16; ++ks) {
        const int cur = ks & 1;
        if (ks < 15) {
            const int k0 = (ks + 1) * 32;
            if (aok) areg = *(const us4*)(aptr + k0);
#pragma unroll
            for (int jj = 0; jj < 4; jj++) breg[jj] = *(const us8*)(bptr + k0 + jj * 8);
        }
        short8 af0 = *(const short8*)&Asm[cur][l15][g * 8];
        short8 af1 = *(const short8*)&Asm[cur][16 + l15][g * 8];
#pragma unroll
        for (int fj = 0; fj < 4; fj++) {
            short8 bf = *(const short8*)&Bsm[cur][wid * 64 + fj * 16 + l15][g * 8];
            acc[0][fj] = __builtin_amdgcn_mfma_f32_16x16x32_bf16(af0, bf, acc[0][fj], 0, 0, 0);
            acc[1][fj] = __builtin_amdgcn_mfma_f32_16x16x32_bf16(af1, bf, acc[1][fj], 0, 0, 0);
        }
        if (ks < 15) {
            const int nb = cur ^ 1;
            *(us4*)&Asm[nb][arow][akseg] = areg;
#pragma unroll
            for (int jj = 0; jj < 4; jj++) *(us8*)&Bsm[nb][t][jj * 8] = breg[jj];
        }
        __syncthreads();
    }

    const int wcol0 = wid * 64;
    float bl[4], wl[4], wg[4], wo[4];
#pragma unroll
    for (int fj = 0; fj < 4; fj++) {
        int col = wcol0 + fj * 16 + l15;
        bl[fj] = b_l[col]; wl[fj] = W_rel[col];
        wg[fj] = W_gate[col]; wo[fj] = W_root[col];
    }
#pragma unroll
    for (int fi = 0; fi < 2; fi++) {
#pragma unroll
        for (int r = 0; r < 4; r++) {
            int row = row0 + fi * 16 + g * 4 + r;
            float py = 0.f, pc = 0.f, pr = 0.f;
#pragma unroll
            for (int fj = 0; fj < 4; fj++) {
                float v = fmaxf(acc[fi][fj][r] + bl[fj], 0.f);
                if (row < NN)
                    xout[(size_t)row * DD + wcol0 + fj * 16 + l15] = v;
                py = fmaf(v, wl[fj], py);
                pc = fmaf(v, wg[fj], pc);
                pr = fmaf(v, wo[fj], pr);
            }
#pragma unroll
            for (int off = 1; off < 16; off <<= 1) {
                py += __shfl_xor(py, off);
                pc += __shfl_xor(pc, off);
                pr += __shfl_xor(pr, off);
            }
            if (l15 == 0) {
                int rl = fi * 16 + g * 4 + r;
                Ys[wid][rl] = py; Cs[wid][rl] = pc; Rs[wid][rl] = pr;
            }
        }
    }
    __syncthreads();
    if (t < 32) {
        int row = row0 + t;
        if (row < NN) {
            y[row]    = Ys[0][t] + Ys[1][t] + Ys[2][t] + Ys[3][t];
            cvec[row] = Cs[0][t] + Cs[1][t] + Cs[2][t] + Cs[3][t];
            rvec[row] = Rs[0][t] + Rs[1][t] + Rs[2][t] + Rs[3][t];
        }
    }
}

// ---------------- 6. gather y + score + key -------------------------------
__global__ __launch_bounds__(256) void gather_score(
    const float* __restrict__ y, const float* __restrict__ r,
    const float* __restrict__ b_rel, const int* __restrict__ csr,
    const int* __restrict__ start,
    float* __restrict__ score, uint* __restrict__ key) {
    int gt   = blockIdx.x * 256 + threadIdx.x;
    int node = gt >> 4, l = gt & 15;
    if (node >= NN) return;
    int s = start[node], e = start[node + 1];
    float acc = 0.f;
    for (int j = s + l; j < e; j += 16) acc += y[csr[j]];
#pragma unroll
    for (int o = 8; o; o >>= 1) acc += __shfl_xor(acc, o, 16);
    if (l == 0) {
        float sc = tanhf(acc + b_rel[0] + r[node]);
        score[node] = sc;
        key[node]   = encodeF(sc);
    }
}

// ---------------- 7. radix select v2 --------------------------------------
__global__ __launch_bounds__(1024) void radix_select(
    const uint* __restrict__ key, const float* __restrict__ score,
    const float* __restrict__ cvec,
    float* __restrict__ wsc, float* __restrict__ denom) {
    __shared__ uint  hist[16][260];
    __shared__ uint  sh_prefix, sh_need;
    __shared__ float wred[16];
    __shared__ uint  tick_s;
    const int t = threadIdx.x, wid = t >> 6, lane = t & 63;

    uint  myk[10];
    float mys[10], myl[10];
#pragma unroll
    for (int i = 0; i < 10; i++) {
        int idx = t + i * 1024;
        if (idx < NN) {
            uint k  = key[idx];
            float s = score[idx];
            myk[i] = k; mys[i] = s; myl[i] = s * cvec[idx];
        } else {
            myk[i] = 0u; mys[i] = 0.f; myl[i] = -INFINITY;
        }
    }

    uint prefix = 0, pmask = 0, need = KSEL;
    float vmax = -INFINITY;
    for (int shift = 24; shift >= 0; shift -= 8) {
        for (int i = lane; i < 256; i += 64) hist[wid][i] = 0;
        if (shift == 0) {
#pragma unroll
            for (int i = 0; i < 10; i++) {
                uint k = myk[i];
                if ((k & pmask) == prefix) atomicAdd(&hist[wid][k & 255], 1u);
                if (k >= prefix) vmax = fmaxf(vmax, myl[i]);
            }
        } else {
#pragma unroll
            for (int i = 0; i < 10; i++) {
                uint k = myk[i];
                if ((k & pmask) == prefix)
                    atomicAdd(&hist[wid][(k >> shift) & 255], 1u);
            }
        }
        __syncthreads();
        if (wid == 0) {
            uint4 a = make_uint4(0u, 0u, 0u, 0u);
#pragma unroll
            for (int w = 0; w < 16; w++) {
                uint4 v = *(const uint4*)&hist[w][lane * 4];
                a.x += v.x; a.y += v.y; a.z += v.z; a.w += v.w;
            }
            uint s3 = a.w, s2 = a.z + s3, s1 = a.y + s2, s0 = a.x + s1;
            uint x = s0;
#pragma unroll
            for (int off = 1; off < 64; off <<= 1) {
                uint v = __shfl_down(x, off);
                if (lane + off < 64) x += v;
            }
            uint excl = x - s0;
            uint hi0 = excl + s0, hi1 = excl + s1;
            uint hi2 = excl + s2, hi3 = excl + s3;
            if (need <= hi0 && need > hi0 - a.x) {
                sh_prefix = prefix | ((uint)(lane * 4 + 0) << shift);
                sh_need   = need - (hi0 - a.x);
            }
            if (need <= hi1 && need > hi1 - a.y) {
                sh_prefix = prefix | ((uint)(lane * 4 + 1) << shift);
                sh_need   = need - (hi1 - a.y);
            }
            if (need <= hi2 && need > hi2 - a.z) {
                sh_prefix = prefix | ((uint)(lane * 4 + 2) << shift);
                sh_need   = need - (hi2 - a.z);
            }
            if (need <= hi3 && need > hi3 - a.w) {
                sh_prefix = prefix | ((uint)(lane * 4 + 3) << shift);
                sh_need   = need - (hi3 - a.w);
            }
        }
        __syncthreads();
        prefix = sh_prefix;
        need   = sh_need;
        pmask |= (0xFFu << shift);
    }
    const uint T      = prefix;
    const uint needEq = need;
#pragma unroll
    for (int o = 32; o; o >>= 1) vmax = fmaxf(vmax, __shfl_xor(vmax, o));
    if (lane == 0) wred[wid] = vmax;
    if (t == 0) tick_s = 0;
    __syncthreads();
    float m = wred[0];
#pragma unroll
    for (int w = 1; w < 16; w++) m = fmaxf(m, wred[w]);
    __syncthreads();
    float dsum = 0.f;
#pragma unroll
    for (int i = 0; i < 10; i++) {
        int idx = t + i * 1024;
        if (idx >= NN) continue;
        uint k = myk[i];
        bool selm = (k > T);
        if (k == T) selm = (atomicAdd(&tick_s, 1u) < needEq);
        float wv = 0.f;
        if (selm) {
            float w = expf(myl[i] - m);
            wv   = w * mys[i];
            dsum += w;
        }
        wsc[idx] = wv;
    }
#pragma unroll
    for (int o = 32; o; o >>= 1) dsum += __shfl_xor(dsum, o);
    if (lane == 0) wred[wid] = dsum;
    __syncthreads();
    if (t == 0) {
        float d = 0.f;
#pragma unroll
        for (int w = 0; w < 16; w++) d += wred[w];
        denom[0] = d;
    }
}

// ---------------- 8. weighted row-sum + last-block finalize ---------------
__global__ __launch_bounds__(256) void reduce_rows(
    const float* __restrict__ x, const float* __restrict__ wsc,
    float* __restrict__ part, uint* __restrict__ counter,
    const float* __restrict__ denom, float* __restrict__ out) {
    __shared__ float red[3][DD];
    __shared__ uint  lastdone;
    const int wave = threadIdx.x >> 6;
    const int lane = threadIdx.x & 63;
    const int row0 = (blockIdx.x * 4 + wave) * 16;
    const float* xp = x + lane * 4;
    float4 acc = make_float4(0.f, 0.f, 0.f, 0.f);
    if (row0 < NN) {
#pragma unroll
        for (int rb = 0; rb < 16; rb += 4) {
            int r0 = row0 + rb;
            float w0 = wsc[r0 + 0], w1 = wsc[r0 + 1];
            float w2 = wsc[r0 + 2], w3 = wsc[r0 + 3];
            float4 v0 = *(const float4*)(xp + (size_t)(r0 + 0) * DD);
            float4 v1 = *(const float4*)(xp + (size_t)(r0 + 1) * DD);
            float4 v2 = *(const float4*)(xp + (size_t)(r0 + 2) * DD);
            float4 v3 = *(const float4*)(xp + (size_t)(r0 + 3) * DD);
            acc.x = fmaf(w0, v0.x, fmaf(w1, v1.x, fmaf(w2, v2.x, fmaf(w3, v3.x, acc.x))));
            acc.y = fmaf(w0, v0.y, fmaf(w1, v1.y, fmaf(w2, v2.y, fmaf(w3, v3.y, acc.y))));
            acc.z = fmaf(w0, v0.z, fmaf(w1, v1.z, fmaf(w2, v2.z, fmaf(w3, v3.z, acc.z))));
            acc.w = fmaf(w0, v0.w, fmaf(w1, v1.w, fmaf(w2, v2.w, fmaf(w3, v3.w, acc.w))));
        }
    }
    if (wave > 0) *(float4*)&red[wave - 1][lane * 4] = acc;
    __syncthreads();
    if (wave == 0) {
#pragma unroll
        for (int w = 0; w < 3; w++) {
            float4 rv = *(float4*)&red[w][lane * 4];
            acc.x += rv.x; acc.y += rv.y; acc.z += rv.z; acc.w += rv.w;
        }
        *(float4*)(part + (size_t)blockIdx.x * DD + lane * 4) = acc;
    }
    __threadfence();
    if (threadIdx.x == 0) lastdone = atomicAdd(counter, 1u);
    __syncthreads();
    if (lastdone == NPART - 1) {
        __threadfence();
        int i = threadIdx.x;
        float s = 0.f;
        for (int b = 0; b < NPART; b++) s += part[(size_t)b * DD + i];
        out[i] = s / denom[0];
    }
}

extern "C" void kernel_launch(void* const* d_in, const int* in_sizes, int n_in,
                              void* d_out, int out_size, void* d_ws, size_t ws_size,
                              hipStream_t stream) {
    const float* h      = (const float*)d_in[0];
    const int*   ei     = (const int*)d_in[1];
    const float* W_l    = (const float*)d_in[2];
    const float* b_l    = (const float*)d_in[3];
    const float* W_r    = (const float*)d_in[4];
    const float* W_rel  = (const float*)d_in[5];
    const float* b_rel  = (const float*)d_in[6];
    const float* W_root = (const float*)d_in[7];
    const float* W_gate = (const float*)d_in[8];
    // b_gate (d_in[9]) cancels in softmax
    float* out = (float*)d_out;

    char* p = (char*)d_ws;
    auto alloc = [&p](size_t bytes) {
        char* q = p;
        p += (bytes + 63) & ~(size_t)63;
        return q;
    };
    ushort* Ab    = (ushort*)alloc((size_t)NN * KK * 2);
    uchar*  h8    = (uchar*) alloc((size_t)NN * DD);
    float*  xbuf  = (float*) alloc((size_t)NN * DD * 4);
    ushort* Wt    = (ushort*)alloc((size_t)DD * KK * 2);
    int*    csr   = (int*)   alloc((size_t)NE * 4);
    int*    start = (int*)   alloc((size_t)(NN + 1) * 4);
    int*    cursor= (int*)   alloc((size_t)NN * 4);
    float*  invdeg= (float*) alloc((size_t)NN * 4);
    float*  score = (float*) alloc((size_t)NN * 4);
    uint*   key   = (uint*)  alloc((size_t)NN * 4);
    float*  wsc   = (float*) alloc((size_t)NN * 4);
    float*  denom = (float*) alloc(64);
    float*  part  = (float*) alloc((size_t)NPART * DD * 4);
    float*  y     = (float*) alloc((size_t)NN * 4);
    float*  cbuf  = (float*) alloc((size_t)NN * 4);
    float*  rbuf  = (float*) alloc((size_t)NN * 4);
    // ---- zero-initialized region (contiguous, 40064 B) ----
    int*    degi  = (int*)   alloc((size_t)NN * 4);
    uint*   cnt   = (uint*)  alloc(64);

    zero_bufs   <<<(ZQUADS + 255) / 256, 256, 0, stream>>>((float4*)degi);
    prep        <<<WB + HB + DB, 256, 0, stream>>>(h, W_l, W_r, ei,
                                                   Ab, h8, Wt, degi);
    scan_start  <<<1, 1024, 0, stream>>>(degi, start, cursor, invdeg);
    fill_csr    <<<(NE + 255) / 256, 256, 0, stream>>>(ei, cursor, csr);
    gather_mean <<<(NN + 3) / 4, 256, 0, stream>>>(Ab, h8, csr, start, invdeg);
    gemm_x      <<<(NN + 31) / 32, 256, 0, stream>>>(Ab, Wt, b_l,
                                                     W_rel, W_gate, W_root,
                                                     xbuf, y, cbuf, rbuf);
    gather_score<<<(NN * 16 + 255) / 256, 256, 0, stream>>>(y, rbuf, b_rel, csr,
                                                            start, score, key);
    radix_select<<<1, 1024, 0, stream>>>(key, score, cbuf, wsc, denom);
    reduce_rows <<<NPART, 256, 0, stream>>>(xbuf, wsc, part, cnt, denom, out);
    (void)n_in; (void)in_sizes; (void)out_size; (void)ws_size;
}